// Round 4
// baseline (605.431 us; speedup 1.0000x reference)
//
#include <hip/hip_runtime.h>

namespace {
constexpr int T = 512;
constexpr int BATCH = 512;
constexpr int D = 32;
constexpr int H = 64;
}

__device__ __forceinline__ float rcpf_fast(float x) { return __builtin_amdgcn_rcpf(x); }
__device__ __forceinline__ float sigm(float x) { return rcpf_fast(1.0f + __expf(-x)); }
__device__ __forceinline__ float tanh_fast(float x) {
    return 1.0f - 2.0f * rcpf_fast(__expf(2.0f * x) + 1.0f);
}

// packed fp32 FMA: acc.{lo,hi} += w.{lo,hi} * v.{lo,hi}  (2 FMAs / instruction)
__device__ __forceinline__ void pk4(float2& acc, const float4 w, const float4 v) {
    float2 a0{w.x, w.y}, b0{v.x, v.y};
    asm("v_pk_fma_f32 %0, %1, %2, %0" : "+v"(acc) : "v"(a0), "v"(b0));
    float2 a1{w.z, w.w}, b1{v.z, v.w};
    asm("v_pk_fma_f32 %0, %1, %2, %0" : "+v"(acc) : "v"(a1), "v"(b1));
}

__global__ __launch_bounds__(64, 1) void gru_fused_kernel(
    const float* __restrict__ x,
    const float* __restrict__ w_ih_f, const float* __restrict__ w_hh_f,
    const float* __restrict__ b_ih_f, const float* __restrict__ b_hh_f,
    const float* __restrict__ w_ih_b, const float* __restrict__ b_ih_b,
    const float* __restrict__ b_hh_b,
    const float* __restrict__ fc1_w, const float* __restrict__ fc1_b,
    const float* __restrict__ fc2_w, const float* __restrict__ fc2_b,
    float* __restrict__ out)
{
    const int b = blockIdx.x;   // batch row — ONE WAVE per row, zero barriers
    const int j = threadIdx.x;  // 0..63: lane j owns h-index j (all 3 gates)

    __shared__ float4 x_lds4[T * D / 4];   // 64 KB staged x row
    __shared__ float4 h_lds4[H / 4];       // h broadcast buffer
    __shared__ float4 hb_lds4[H / 4];      // backward-dir state for head
    float* h_lds  = reinterpret_cast<float*>(h_lds4);
    float* hb_lds = reinterpret_cast<float*>(hb_lds4);

    // ---- per-lane weights in registers: rows j, H+j, 2H+j ----
    float4 wrh[16], wzh[16], wnh[16];   // w_hh rows (64 each)
    {
        const float4* pr = reinterpret_cast<const float4*>(w_hh_f + (size_t)j * H);
        const float4* pz = reinterpret_cast<const float4*>(w_hh_f + (size_t)(H + j) * H);
        const float4* pn = reinterpret_cast<const float4*>(w_hh_f + (size_t)(2 * H + j) * H);
        #pragma unroll
        for (int m = 0; m < 16; ++m) { wrh[m] = pr[m]; wzh[m] = pz[m]; wnh[m] = pn[m]; }
    }
    float4 urx[8], uzx[8], unx[8];      // w_ih rows (32 each)
    {
        const float4* pr = reinterpret_cast<const float4*>(w_ih_f + (size_t)j * D);
        const float4* pz = reinterpret_cast<const float4*>(w_ih_f + (size_t)(H + j) * D);
        const float4* pn = reinterpret_cast<const float4*>(w_ih_f + (size_t)(2 * H + j) * D);
        #pragma unroll
        for (int m = 0; m < 8; ++m) { urx[m] = pr[m]; uzx[m] = pz[m]; unx[m] = pn[m]; }
    }

    const float pre_r  = b_ih_f[j]         + b_hh_f[j];
    const float pre_z  = b_ih_f[H + j]     + b_hh_f[H + j];
    const float pre_nx = b_ih_f[2 * H + j];
    const float pre_nh = b_hh_f[2 * H + j];

    // ---- stage x row into LDS (coalesced b128; wave-internal, no barrier) ----
    {
        const float4* xg = reinterpret_cast<const float4*>(x + (size_t)b * T * D);
        #pragma unroll 8
        for (int i = j; i < T * D / 4; i += 64) x_lds4[i] = xg[i];
    }
    h_lds[j] = 0.0f;      // same-wave ordering guarantees visibility
    float hold = 0.0f;    // lane's own h[j] stays in a register

    float4 xw[8];         // current x window (uniform broadcast values)

    for (int t = 0; t < T; ++t) {
        // uniform x reads (all lanes same address -> broadcast, conflict-free)
        const float4* xt4 = x_lds4 + t * (D / 4);
        #pragma unroll
        for (int m = 0; m < 8; ++m) xw[m] = xt4[m];

        float2 pr{pre_r, 0.f}, pz{pre_z, 0.f}, nh{pre_nh, 0.f}, nx{pre_nx, 0.f};

        // x-dot: 48 pk-FMA (independent of h -> fills h-read latency)
        #pragma unroll
        for (int m = 0; m < 8; ++m) {
            pk4(pr, urx[m], xw[m]);
            pk4(pz, uzx[m], xw[m]);
            pk4(nx, unx[m], xw[m]);
        }

        // h-dot: 96 pk-FMA over uniform h broadcast, two half-windows
        {
            float4 hw0[8];
            #pragma unroll
            for (int m = 0; m < 8; ++m) hw0[m] = h_lds4[m];
            #pragma unroll
            for (int m = 0; m < 8; ++m) {
                pk4(pr, wrh[m], hw0[m]);
                pk4(pz, wzh[m], hw0[m]);
                pk4(nh, wnh[m], hw0[m]);
            }
            float4 hw1[8];
            #pragma unroll
            for (int m = 0; m < 8; ++m) hw1[m] = h_lds4[8 + m];
            #pragma unroll
            for (int m = 0; m < 8; ++m) {
                pk4(pr, wrh[8 + m], hw1[m]);
                pk4(pz, wzh[8 + m], hw1[m]);
                pk4(nh, wnh[8 + m], hw1[m]);
            }
        }

        const float r = sigm(pr.x + pr.y);
        const float z = sigm(pz.x + pz.y);
        const float n = tanh_fast((nx.x + nx.y) + r * (nh.x + nh.y));
        const float hnew = n + z * (hold - n);   // (1-z)n + z*hold
        hold = hnew;
        h_lds[j] = hnew;   // in-order DS pipe: visible to next step's reads
    }

    // ---- epilogue (still one wave, still no barriers) ----
    // backward direction: ONE step from h0=0 on x[T-1] (xw still holds it)
    {
        const float4* pr = reinterpret_cast<const float4*>(w_ih_b + (size_t)j * D);
        const float4* pz = reinterpret_cast<const float4*>(w_ih_b + (size_t)(H + j) * D);
        const float4* pn = reinterpret_cast<const float4*>(w_ih_b + (size_t)(2 * H + j) * D);
        float2 ar{0.f, 0.f}, az{0.f, 0.f}, an{0.f, 0.f};
        #pragma unroll
        for (int m = 0; m < 8; ++m) {
            pk4(ar, pr[m], xw[m]);
            pk4(az, pz[m], xw[m]);
            pk4(an, pn[m], xw[m]);
        }
        const float rb = sigm(ar.x + ar.y + b_ih_b[j]         + b_hh_b[j]);
        const float zb = sigm(az.x + az.y + b_ih_b[H + j]     + b_hh_b[H + j]);
        const float nb = tanh_fast(an.x + an.y + b_ih_b[2 * H + j]
                                   + rb * b_hh_b[2 * H + j]);
        hb_lds[j] = (1.0f - zb) * nb;   // z*h0 = 0
    }

    // head: h1 = leaky(fc1_w @ [h_f, h_b] + fc1_b); out = fc2_w @ h1 + fc2_b
    {
        const float4* w1 = reinterpret_cast<const float4*>(fc1_w + (size_t)j * (2 * H));
        float2 acc{fc1_b[j], 0.f};
        #pragma unroll
        for (int m = 0; m < 16; ++m) pk4(acc, w1[m], h_lds4[m]);        // fw half
        #pragma unroll
        for (int m = 0; m < 16; ++m) pk4(acc, w1[16 + m], hb_lds4[m]);  // bw half
        float a = acc.x + acc.y;
        a = (a >= 0.0f) ? a : 0.2f * a;
        float red = a * fc2_w[j];
        #pragma unroll
        for (int off = 32; off > 0; off >>= 1) red += __shfl_xor(red, off);
        if (j == 0) out[b] = red + fc2_b[0];
    }
}

extern "C" void kernel_launch(void* const* d_in, const int* in_sizes, int n_in,
                              void* d_out, int out_size, void* d_ws, size_t ws_size,
                              hipStream_t stream) {
    const float* x      = (const float*)d_in[0];
    const float* w_ih_f = (const float*)d_in[1];
    const float* w_hh_f = (const float*)d_in[2];
    const float* b_ih_f = (const float*)d_in[3];
    const float* b_hh_f = (const float*)d_in[4];
    const float* w_ih_b = (const float*)d_in[5];
    // d_in[6] = w_hh_b: unused (backward direction runs exactly one step from h0=0)
    const float* b_ih_b = (const float*)d_in[7];
    const float* b_hh_b = (const float*)d_in[8];
    const float* fc1_w  = (const float*)d_in[9];
    const float* fc1_b  = (const float*)d_in[10];
    const float* fc2_w  = (const float*)d_in[11];
    const float* fc2_b  = (const float*)d_in[12];
    float* out = (float*)d_out;

    gru_fused_kernel<<<BATCH, 64, 0, stream>>>(
        x, w_ih_f, w_hh_f, b_ih_f, b_hh_f,
        w_ih_b, b_ih_b, b_hh_b,
        fc1_w, fc1_b, fc2_w, fc2_b, out);
}

// Round 6
// 269.811 us; speedup vs baseline: 2.2439x; 2.2439x over previous
//
#include <hip/hip_runtime.h>

namespace {
constexpr int T = 512;
constexpr int BATCH = 512;
constexpr int D = 32;
constexpr int H = 64;
constexpr int THREADS = 256;  // 4 waves/row; lane = (j = tid>>2, q = tid&3)
}

__device__ __forceinline__ float rcpf(float x) { return __builtin_amdgcn_rcpf(x); }
__device__ __forceinline__ float sigm(float x) { return rcpf(1.0f + __expf(-x)); }
__device__ __forceinline__ float tanh_fast(float x) {
    // 1 - 2/(e^{2x}+1); saturates via inf/0 at extremes
    return 1.0f - 2.0f * rcpf(__expf(2.0f * x) + 1.0f);
}

// packed fp32 FMA: acc.{lo,hi} += w.{lo,hi} * v.{lo,hi}  (2 FMAs / instruction)
__device__ __forceinline__ void pk4(float2& acc, const float4 w, const float4 v) {
    float2 a0{w.x, w.y}, b0{v.x, v.y};
    asm("v_pk_fma_f32 %0, %1, %2, %0" : "+v"(acc) : "v"(a0), "v"(b0));
    float2 a1{w.z, w.w}, b1{v.z, v.w};
    asm("v_pk_fma_f32 %0, %1, %2, %0" : "+v"(acc) : "v"(a1), "v"(b1));
}

__global__ __launch_bounds__(THREADS) void gru_fused_kernel(
    const float* __restrict__ x,
    const float* __restrict__ w_ih_f, const float* __restrict__ w_hh_f,
    const float* __restrict__ b_ih_f, const float* __restrict__ b_hh_f,
    const float* __restrict__ w_ih_b, const float* __restrict__ b_ih_b,
    const float* __restrict__ b_hh_b,
    const float* __restrict__ fc1_w, const float* __restrict__ fc1_b,
    const float* __restrict__ fc2_w, const float* __restrict__ fc2_b,
    float* __restrict__ out)
{
    const int b   = blockIdx.x;   // batch row
    const int tid = threadIdx.x;
    const int j   = tid >> 2;     // h-index 0..63 — owns all 3 gates for this j
    const int q   = tid & 3;      // K-split quarter
    const int kh0 = q * 16;      // h-k slice [kh0, kh0+16)
    const int kx0 = q * 8;       // x-k slice [kx0, kx0+8)

    __shared__ float4 x_lds[T * D / 4];              // 64 KB staged x row
    __shared__ __align__(16) float h_lds[2][H];      // double-buffered h
    __shared__ float last_lds[2 * H];

    // ---- per-lane weight slices in registers (72 floats, kept as float4) ----
    float4 wr4[4], wz4[4], wn4[4], ur4[2], uz4[2], un4[2];
    {
        const float4* pr = reinterpret_cast<const float4*>(w_hh_f + (size_t)j * H + kh0);
        const float4* pz = reinterpret_cast<const float4*>(w_hh_f + (size_t)(H + j) * H + kh0);
        const float4* pn = reinterpret_cast<const float4*>(w_hh_f + (size_t)(2 * H + j) * H + kh0);
        #pragma unroll
        for (int m = 0; m < 4; ++m) { wr4[m] = pr[m]; wz4[m] = pz[m]; wn4[m] = pn[m]; }
        const float4* qr = reinterpret_cast<const float4*>(w_ih_f + (size_t)j * D + kx0);
        const float4* qz = reinterpret_cast<const float4*>(w_ih_f + (size_t)(H + j) * D + kx0);
        const float4* qn = reinterpret_cast<const float4*>(w_ih_f + (size_t)(2 * H + j) * D + kx0);
        #pragma unroll
        for (int m = 0; m < 2; ++m) { ur4[m] = qr[m]; uz4[m] = qz[m]; un4[m] = qn[m]; }
    }

    // biases: added exactly ONCE, AFTER the 4-lane K-split reduction
    const float pre_r  = b_ih_f[j]         + b_hh_f[j];
    const float pre_z  = b_ih_f[H + j]     + b_hh_f[H + j];
    const float pre_nx = b_ih_f[2 * H + j];
    const float pre_nh = b_hh_f[2 * H + j];

    // ---- stage x row into LDS (coalesced float4) ----
    {
        const float4* xg = reinterpret_cast<const float4*>(x + (size_t)b * T * D);
        #pragma unroll 4
        for (int i = tid; i < T * D / 4; i += THREADS) x_lds[i] = xg[i];
    }
    if (tid < H) h_lds[0][tid] = 0.0f;
    __syncthreads();

    // ---- x-dot for t=0 (bias-free partials; n-x part fully reduced) ----
    float2 axr{0.f, 0.f}, axz{0.f, 0.f};
    float  vnx;
    {
        const float4* xt4 = x_lds + q * 2;
        float4 a = xt4[0], c = xt4[1];
        float2 axn{0.f, 0.f};
        pk4(axr, ur4[0], a); pk4(axr, ur4[1], c);
        pk4(axz, uz4[0], a); pk4(axz, uz4[1], c);
        pk4(axn, un4[0], a); pk4(axn, un4[1], c);
        vnx = axn.x + axn.y;
        vnx += __shfl_xor(vnx, 1); vnx += __shfl_xor(vnx, 2);
    }

    float hold = 0.0f;

    for (int t = 0; t < T; ++t) {
        const int cur = t & 1, nxt = cur ^ 1;

        // h slice (LDS broadcast; 4 addresses/instr, 2-way bank alias = free)
        float4 hh[4];
        {
            const float4* hp = reinterpret_cast<const float4*>(&h_lds[cur][kh0]);
            #pragma unroll
            for (int m = 0; m < 4; ++m) hh[m] = hp[m];
        }

        // h-dot on top of prefetched x partials: 24 pk-FMA
        float2 pr = axr, pz = axz, nh{0.f, 0.f};
        #pragma unroll
        for (int m = 0; m < 4; ++m) pk4(pr, wr4[m], hh[m]);
        #pragma unroll
        for (int m = 0; m < 4; ++m) pk4(pz, wz4[m], hh[m]);
        #pragma unroll
        for (int m = 0; m < 4; ++m) pk4(nh, wn4[m], hh[m]);

        // reduce K-split partials across the 4 lanes sharing j
        float vr  = pr.x + pr.y;
        float vz  = pz.x + pz.y;
        float vnh = nh.x + nh.y;
        vr  += __shfl_xor(vr, 1);  vr  += __shfl_xor(vr, 2);
        vz  += __shfl_xor(vz, 1);  vz  += __shfl_xor(vz, 2);
        vnh += __shfl_xor(vnh, 1); vnh += __shfl_xor(vnh, 2);

        const float r = sigm(vr + pre_r);
        const float z = sigm(vz + pre_z);
        const float n = tanh_fast(vnx + pre_nx + r * (vnh + pre_nh));
        const float hnew = n + z * (hold - n);   // (1-z)n + z*hold
        hold = hnew;
        if (q == 0) h_lds[nxt][j] = hnew;

        // prefetch next step's x-dot + reduce its n-part (off the h critical
        // path: overlaps the barrier wait)
        {
            const int tn = (t + 1) & (T - 1);
            const float4* xt4 = x_lds + tn * (D / 4) + q * 2;
            float4 a = xt4[0], c = xt4[1];
            axr = {0.f, 0.f}; axz = {0.f, 0.f};
            float2 axn{0.f, 0.f};
            pk4(axr, ur4[0], a); pk4(axr, ur4[1], c);
            pk4(axz, uz4[0], a); pk4(axz, uz4[1], c);
            pk4(axn, un4[0], a); pk4(axn, un4[1], c);
            vnx = axn.x + axn.y;
            vnx += __shfl_xor(vnx, 1); vnx += __shfl_xor(vnx, 2);
        }

        __syncthreads();   // single barrier per step
    }

    // ---- epilogue ----
    const int wave = tid >> 6, lane = tid & 63;

    // forward final state (T even -> buffer 0)
    if (wave == 0) last_lds[lane] = h_lds[T & 1][lane];

    // backward direction: exactly ONE step from h0 = 0 on x[b][T-1][:]
    if (wave == 1) {
        const float* xT = reinterpret_cast<const float*>(x_lds) + (T - 1) * D;
        const int jj = lane;
        float xr = b_ih_b[jj];
        float xz = b_ih_b[H + jj];
        float xn = b_ih_b[2 * H + jj];
        #pragma unroll
        for (int k = 0; k < D; ++k) {
            const float xv = xT[k];
            xr = fmaf(w_ih_b[(size_t)jj * D + k],           xv, xr);
            xz = fmaf(w_ih_b[(size_t)(H + jj) * D + k],     xv, xz);
            xn = fmaf(w_ih_b[(size_t)(2 * H + jj) * D + k], xv, xn);
        }
        const float r = sigm(xr + b_hh_b[jj]);
        const float z = sigm(xz + b_hh_b[H + jj]);
        const float n = tanh_fast(xn + r * b_hh_b[2 * H + jj]);
        last_lds[H + jj] = (1.0f - z) * n;   // z*h0 = 0
    }
    __syncthreads();

    // head: h1 = leaky(fc1_w @ last + fc1_b); out = fc2_w @ h1 + fc2_b
    if (wave == 0) {
        float acc = fc1_b[lane];
        const float* w1 = fc1_w + (size_t)lane * (2 * H);
        #pragma unroll 8
        for (int c = 0; c < 2 * H; ++c) acc = fmaf(w1[c], last_lds[c], acc);
        acc = (acc >= 0.0f) ? acc : 0.2f * acc;
        float red = acc * fc2_w[lane];
        #pragma unroll
        for (int off = 32; off > 0; off >>= 1)
            red += __shfl_down(red, off);
        if (lane == 0) out[b] = red + fc2_b[0];
    }
}

extern "C" void kernel_launch(void* const* d_in, const int* in_sizes, int n_in,
                              void* d_out, int out_size, void* d_ws, size_t ws_size,
                              hipStream_t stream) {
    const float* x      = (const float*)d_in[0];
    const float* w_ih_f = (const float*)d_in[1];
    const float* w_hh_f = (const float*)d_in[2];
    const float* b_ih_f = (const float*)d_in[3];
    const float* b_hh_f = (const float*)d_in[4];
    const float* w_ih_b = (const float*)d_in[5];
    // d_in[6] = w_hh_b: unused (backward direction runs exactly one step from h0=0)
    const float* b_ih_b = (const float*)d_in[7];
    const float* b_hh_b = (const float*)d_in[8];
    const float* fc1_w  = (const float*)d_in[9];
    const float* fc1_b  = (const float*)d_in[10];
    const float* fc2_w  = (const float*)d_in[11];
    const float* fc2_b  = (const float*)d_in[12];
    float* out = (float*)d_out;

    gru_fused_kernel<<<BATCH, THREADS, 0, stream>>>(
        x, w_ih_f, w_hh_f, b_ih_f, b_hh_f,
        w_ih_b, b_ih_b, b_hh_b,
        fc1_w, fc1_b, fc2_w, fc2_b, out);
}

// Round 7
// 209.743 us; speedup vs baseline: 2.8865x; 1.2864x over previous
//
#include <hip/hip_runtime.h>

namespace {
constexpr int T = 512;
constexpr int BATCH = 512;
constexpr int D = 32;
constexpr int H = 64;
constexpr int THREADS = 256;  // 4 waves/row; lane = (j = tid>>2, q = tid&3)
}

typedef float v2f __attribute__((ext_vector_type(2)));

__device__ __forceinline__ float rcpf(float x) { return __builtin_amdgcn_rcpf(x); }
__device__ __forceinline__ float sigm(float x) { return rcpf(1.0f + __expf(-x)); }
__device__ __forceinline__ float tanh_fast(float x) {
    // 1 - 2/(e^{2x}+1); saturates via inf/0 at extremes
    return 1.0f - 2.0f * rcpf(__expf(2.0f * x) + 1.0f);
}

// packed fp32 FMA on native 64-bit vector registers: no operand repacking
__device__ __forceinline__ void pk2(v2f& acc, v2f w, v2f v) {
    asm("v_pk_fma_f32 %0, %1, %2, %0" : "+v"(acc) : "v"(w), "v"(v));
}

// sum across the 4 lanes of a DPP quad (lanes 4k..4k+3) — pure VALU, no LDS
__device__ __forceinline__ float quad_sum(float v) {
    int i = __builtin_bit_cast(int, v);
    float t = __builtin_bit_cast(float,
        __builtin_amdgcn_update_dpp(0, i, 0xB1, 0xF, 0xF, true)); // quad_perm [1,0,3,2]
    v += t;
    i = __builtin_bit_cast(int, v);
    t = __builtin_bit_cast(float,
        __builtin_amdgcn_update_dpp(0, i, 0x4E, 0xF, 0xF, true)); // quad_perm [2,3,0,1]
    return v + t;
}

__global__ __launch_bounds__(THREADS) void gru_fused_kernel(
    const float* __restrict__ x,
    const float* __restrict__ w_ih_f, const float* __restrict__ w_hh_f,
    const float* __restrict__ b_ih_f, const float* __restrict__ b_hh_f,
    const float* __restrict__ w_ih_b, const float* __restrict__ b_ih_b,
    const float* __restrict__ b_hh_b,
    const float* __restrict__ fc1_w, const float* __restrict__ fc1_b,
    const float* __restrict__ fc2_w, const float* __restrict__ fc2_b,
    float* __restrict__ out)
{
    const int b   = blockIdx.x;   // batch row
    const int tid = threadIdx.x;
    const int j   = tid >> 2;     // h-index 0..63 — owns all 3 gates for this j
    const int q   = tid & 3;      // K-split quarter (= DPP quad lane)
    const int kh0 = q * 16;       // h-k slice [kh0, kh0+16)
    const int kx0 = q * 8;        // x-k slice [kx0, kx0+8)

    __shared__ v2f x_lds[T * D / 2];                 // 64 KB staged x row
    __shared__ __align__(16) float h_lds[2][H];      // double-buffered h
    __shared__ float last_lds[2 * H];

    // ---- per-lane weight slices in registers as native v2f (72 floats) ----
    v2f wr2[8], wz2[8], wn2[8], ur2[4], uz2[4], un2[4];
    {
        const v2f* pr = reinterpret_cast<const v2f*>(w_hh_f + (size_t)j * H + kh0);
        const v2f* pz = reinterpret_cast<const v2f*>(w_hh_f + (size_t)(H + j) * H + kh0);
        const v2f* pn = reinterpret_cast<const v2f*>(w_hh_f + (size_t)(2 * H + j) * H + kh0);
        #pragma unroll
        for (int m = 0; m < 8; ++m) { wr2[m] = pr[m]; wz2[m] = pz[m]; wn2[m] = pn[m]; }
        const v2f* qr = reinterpret_cast<const v2f*>(w_ih_f + (size_t)j * D + kx0);
        const v2f* qz = reinterpret_cast<const v2f*>(w_ih_f + (size_t)(H + j) * D + kx0);
        const v2f* qn = reinterpret_cast<const v2f*>(w_ih_f + (size_t)(2 * H + j) * D + kx0);
        #pragma unroll
        for (int m = 0; m < 4; ++m) { ur2[m] = qr[m]; uz2[m] = qz[m]; un2[m] = qn[m]; }
    }

    // biases: added exactly ONCE, AFTER the quad reduction
    const float pre_r  = b_ih_f[j]         + b_hh_f[j];
    const float pre_z  = b_ih_f[H + j]     + b_hh_f[H + j];
    const float pre_nx = b_ih_f[2 * H + j];
    const float pre_nh = b_hh_f[2 * H + j];

    // ---- stage x row into LDS (coalesced float4) ----
    {
        const float4* xg  = reinterpret_cast<const float4*>(x + (size_t)b * T * D);
        float4*       xl4 = reinterpret_cast<float4*>(x_lds);
        #pragma unroll 4
        for (int i = tid; i < T * D / 4; i += THREADS) xl4[i] = xg[i];
    }
    if (tid < H) h_lds[0][tid] = 0.0f;
    __syncthreads();

    // ---- x-dot for t=0 (bias-free partials; n-x part fully reduced) ----
    v2f axr = {0.f, 0.f}, axz = {0.f, 0.f};
    float vnx;
    {
        const v2f* xt2 = x_lds + q * 4;   // t=0: offset t*16 + q*4
        v2f x0 = xt2[0], x1 = xt2[1], x2 = xt2[2], x3 = xt2[3];
        v2f axn = {0.f, 0.f};
        pk2(axr, ur2[0], x0); pk2(axr, ur2[1], x1); pk2(axr, ur2[2], x2); pk2(axr, ur2[3], x3);
        pk2(axz, uz2[0], x0); pk2(axz, uz2[1], x1); pk2(axz, uz2[2], x2); pk2(axz, uz2[3], x3);
        pk2(axn, un2[0], x0); pk2(axn, un2[1], x1); pk2(axn, un2[2], x2); pk2(axn, un2[3], x3);
        vnx = quad_sum(axn.x + axn.y);
    }

    float hold = 0.0f;

    for (int t = 0; t < T; ++t) {
        const int cur = t & 1, nxt = cur ^ 1;

        // h slice as native v2f (ds_read_b64; 2-way bank alias = free)
        v2f hh[8];
        {
            const v2f* hp = reinterpret_cast<const v2f*>(&h_lds[cur][kh0]);
            #pragma unroll
            for (int m = 0; m < 8; ++m) hh[m] = hp[m];
        }

        // h-dot on top of prefetched x partials: 24 pk-FMA, zero repacking
        v2f pr = axr, pz = axz, nh = {0.f, 0.f};
        #pragma unroll
        for (int m = 0; m < 8; ++m) pk2(pr, wr2[m], hh[m]);
        #pragma unroll
        for (int m = 0; m < 8; ++m) pk2(pz, wz2[m], hh[m]);
        #pragma unroll
        for (int m = 0; m < 8; ++m) pk2(nh, wn2[m], hh[m]);

        // quad reduction: pure-VALU DPP butterflies (no LDS round trips)
        const float vr  = quad_sum(pr.x + pr.y);
        const float vz  = quad_sum(pz.x + pz.y);
        const float vnh = quad_sum(nh.x + nh.y);

        const float r = sigm(vr + pre_r);
        const float z = sigm(vz + pre_z);
        const float n = tanh_fast(vnx + pre_nx + r * (vnh + pre_nh));
        const float hnew = n + z * (hold - n);   // (1-z)n + z*hold
        hold = hnew;
        if (q == 0) h_lds[nxt][j] = hnew;

        // prefetch next step's x partials (off the h critical path)
        {
            const int tn = (t + 1) & (T - 1);
            const v2f* xt2 = x_lds + tn * 16 + q * 4;
            v2f x0 = xt2[0], x1 = xt2[1], x2 = xt2[2], x3 = xt2[3];
            axr = {0.f, 0.f}; axz = {0.f, 0.f};
            v2f axn = {0.f, 0.f};
            pk2(axr, ur2[0], x0); pk2(axr, ur2[1], x1); pk2(axr, ur2[2], x2); pk2(axr, ur2[3], x3);
            pk2(axz, uz2[0], x0); pk2(axz, uz2[1], x1); pk2(axz, uz2[2], x2); pk2(axz, uz2[3], x3);
            pk2(axn, un2[0], x0); pk2(axn, un2[1], x1); pk2(axn, un2[2], x2); pk2(axn, un2[3], x3);
            vnx = quad_sum(axn.x + axn.y);
        }

        __syncthreads();   // single barrier per step
    }

    // ---- epilogue ----
    const int wave = tid >> 6, lane = tid & 63;

    // forward final state (T even -> buffer 0)
    if (wave == 0) last_lds[lane] = h_lds[T & 1][lane];

    // backward direction: exactly ONE step from h0 = 0 on x[b][T-1][:]
    if (wave == 1) {
        const float* xT = reinterpret_cast<const float*>(x_lds) + (T - 1) * D;
        const int jj = lane;
        float xr = b_ih_b[jj];
        float xz = b_ih_b[H + jj];
        float xn = b_ih_b[2 * H + jj];
        #pragma unroll
        for (int k = 0; k < D; ++k) {
            const float xv = xT[k];
            xr = fmaf(w_ih_b[(size_t)jj * D + k],           xv, xr);
            xz = fmaf(w_ih_b[(size_t)(H + jj) * D + k],     xv, xz);
            xn = fmaf(w_ih_b[(size_t)(2 * H + jj) * D + k], xv, xn);
        }
        const float r = sigm(xr + b_hh_b[jj]);
        const float z = sigm(xz + b_hh_b[H + jj]);
        const float n = tanh_fast(xn + r * b_hh_b[2 * H + jj]);
        last_lds[H + jj] = (1.0f - z) * n;   // z*h0 = 0
    }
    __syncthreads();

    // head: h1 = leaky(fc1_w @ last + fc1_b); out = fc2_w @ h1 + fc2_b
    if (wave == 0) {
        float acc = fc1_b[lane];
        const float* w1 = fc1_w + (size_t)lane * (2 * H);
        #pragma unroll 8
        for (int c = 0; c < 2 * H; ++c) acc = fmaf(w1[c], last_lds[c], acc);
        acc = (acc >= 0.0f) ? acc : 0.2f * acc;
        float red = acc * fc2_w[lane];
        #pragma unroll
        for (int off = 32; off > 0; off >>= 1)
            red += __shfl_down(red, off);
        if (lane == 0) out[b] = red + fc2_b[0];
    }
}

extern "C" void kernel_launch(void* const* d_in, const int* in_sizes, int n_in,
                              void* d_out, int out_size, void* d_ws, size_t ws_size,
                              hipStream_t stream) {
    const float* x      = (const float*)d_in[0];
    const float* w_ih_f = (const float*)d_in[1];
    const float* w_hh_f = (const float*)d_in[2];
    const float* b_ih_f = (const float*)d_in[3];
    const float* b_hh_f = (const float*)d_in[4];
    const float* w_ih_b = (const float*)d_in[5];
    // d_in[6] = w_hh_b: unused (backward direction runs exactly one step from h0=0)
    const float* b_ih_b = (const float*)d_in[7];
    const float* b_hh_b = (const float*)d_in[8];
    const float* fc1_w  = (const float*)d_in[9];
    const float* fc1_b  = (const float*)d_in[10];
    const float* fc2_w  = (const float*)d_in[11];
    const float* fc2_b  = (const float*)d_in[12];
    float* out = (float*)d_out;

    gru_fused_kernel<<<BATCH, THREADS, 0, stream>>>(
        x, w_ih_f, w_hh_f, b_ih_f, b_hh_f,
        w_ih_b, b_ih_b, b_hh_b,
        fc1_w, fc1_b, fc2_w, fc2_b, out);
}